// Round 5
// baseline (294.919 us; speedup 1.0000x reference)
//
#include <hip/hip_runtime.h>
#include <hip/hip_fp16.h>

typedef _Float16 half8 __attribute__((ext_vector_type(8)));
typedef float floatx4 __attribute__((ext_vector_type(4)));

// wperm layout (halfs): hi at [0, WLO_OFF), lo at [WLO_OFF, 2*WLO_OFF)
#define WLO_OFF (6 * 512 * 512)
#define WSTRIDE ((size_t)(8 * 16 * 2048))  // per-W-matrix stride in halfs

// ---------------------------------------------------------------------------
// P1: 6 W matrices [512(k) x 512(n)] fp32 -> fp16 hi + lo (lo = fp16(W - hi),
// ~22-bit effective mantissa), MFMA B-fragment order: tile(w, nt, ki) is
// 4096 B; chunk (u,l) at u*1024 + l*16 holds B[k0+8*(l>>4)+j][n0+16u+(l&15)].
// ---------------------------------------------------------------------------
__global__ __launch_bounds__(256) void permute_w(
    const float* __restrict__ Wir, const float* __restrict__ Whr,
    const float* __restrict__ Wiz, const float* __restrict__ Whz,
    const float* __restrict__ Win, const float* __restrict__ Whn,
    _Float16* __restrict__ wperm) {
  __shared__ __align__(16) float tile[32 * 68];
  const int b = blockIdx.x;
  const int w = b >> 7;
  const int rem = b & 127;
  const int ki = rem >> 3;
  const int nt = rem & 7;
  const float* W = (w == 0) ? Wir : (w == 1) ? Whr : (w == 2) ? Wiz
                 : (w == 3) ? Whz : (w == 4) ? Win : Whn;
  const int k0 = ki * 32, n0 = nt * 64;
  const int t = threadIdx.x;

  const int kk = t >> 3;
  const int nn = (t & 7) * 8;
  const float* src = W + (k0 + kk) * 512 + n0 + nn;
  float4 f0 = *(const float4*)(src);
  float4 f1 = *(const float4*)(src + 4);
  float* drow = tile + kk * 68 + nn;
  *(float4*)(drow) = f0;
  *(float4*)(drow + 4) = f1;
  __syncthreads();

  const int u = t >> 6, l = t & 63;
  const int nloc = 16 * u + (l & 15);
  const int kbase = 8 * (l >> 4);
  half8 vh, vl;
#pragma unroll
  for (int j = 0; j < 8; ++j) {
    float f = tile[(kbase + j) * 68 + nloc];
    _Float16 hiv = (_Float16)f;
    vh[j] = hiv;
    vl[j] = (_Float16)(f - (float)hiv);
  }
  const size_t off = ((size_t)((w * 8 + nt) * 16 + ki)) * 2048 + t * 8;
  *(half8*)(wperm + off) = vh;
  *(half8*)(wperm + WLO_OFF + off) = vl;
}

__device__ __forceinline__ void cvt_hilo(const float4 a, const float4 b,
                                         half8& hi, half8& lo) {
  const float v[8] = {a.x, a.y, a.z, a.w, b.x, b.y, b.z, b.w};
#pragma unroll
  for (int j = 0; j < 8; ++j) {
    _Float16 hv = (_Float16)v[j];
    hi[j] = hv;
    lo[j] = (_Float16)(v[j] - (float)hv);
  }
}

// ---------------------------------------------------------------------------
// Fused GRU (structure identical to R4). ONE change: the block swizzle.
// R4 put nt = bid&7 (nt pinned per XCD) -> the 8 nt-blocks sharing one
// 512 KB x/h tile ran on 8 different XCDs -> each XCD streamed all 64 MB
// of x/h through its 4 MB L2 (FETCH 304 MB, fill-BW bound at ~1.7 TB/s).
// Now: mt is XCD-partitioned and the 8 nt-siblings of each mt launch
// adjacently on ONE XCD -> x/h fetched ~once (resident set 8 x 512 KB =
// 4 MB = L2). W becomes XCD-broadcast (12.6 MB, L3-served) - a 5x-smaller
// stream than x/h was.
// ---------------------------------------------------------------------------
__global__ __launch_bounds__(256, 2) void gru_fused(
    const float* __restrict__ x, const float* __restrict__ h,
    const _Float16* __restrict__ wperm,
    const float* __restrict__ br, const float* __restrict__ bz,
    const float* __restrict__ bn, float* __restrict__ out) {
  __shared__ __align__(16) _Float16 ldsXh[4096];  // 8 KB each, 32 KB total
  __shared__ __align__(16) _Float16 ldsXl[4096];
  __shared__ __align__(16) _Float16 ldsHh[4096];
  __shared__ __align__(16) _Float16 ldsHl[4096];

  const int t = threadIdx.x;
  const int lane = t & 63;
  const int wv = t >> 6;
  const int wm = wv >> 1;
  const int wn = wv & 1;
  const int bid = blockIdx.x;
  // --- XCD-partitioned-by-mt swizzle ---
  const int xcd = bid & 7;        // HW round-robin dispatch target
  const int uu = bid >> 3;
  const int nt = uu & 7;          // fastest: 8 nt-siblings adjacent on one XCD
  const int mt = ((uu >> 3) << 3) | xcd;  // mt owned by exactly one XCD
  const int m0 = mt * 128;
  const int n0 = nt * 64;
  const _Float16* whi = wperm;
  const _Float16* wlo = wperm + WLO_OFF;

  floatx4 acc_r[4][2] = {};
  floatx4 acc_z[4][2] = {};
  floatx4 acc_in[4][2] = {};
  floatx4 acc_hn[4][2] = {};

  // staging chunks: c in {t, t+256}; row m = 16*(c>>6) + (c&15),
  // k offset = 8*((c&63)>>4); chunk written at base + c*8 halfs.
  const int c0 = t, c1 = t + 256;
  const int l0 = c0 & 63, l1 = c1 & 63;
  const int mA0 = 16 * (c0 >> 6) + (l0 & 15), kA0 = 8 * (l0 >> 4);
  const int mA1 = 16 * (c1 >> 6) + (l1 & 15), kA1 = 8 * (l1 >> 4);
  const float* pxb0 = x + (size_t)(m0 + mA0) * 512 + kA0;
  const float* pxb1 = x + (size_t)(m0 + mA1) * 512 + kA1;
  const float* phb0 = h + (size_t)(m0 + mA0) * 512 + kA0;
  const float* phb1 = h + (size_t)(m0 + mA1) * 512 + kA1;

  // pre-loop: load + convert kt=0 staging data
  half8 sth[4], stl[4];
  cvt_hilo(*(const float4*)pxb0, *(const float4*)(pxb0 + 4), sth[0], stl[0]);
  cvt_hilo(*(const float4*)pxb1, *(const float4*)(pxb1 + 4), sth[1], stl[1]);
  cvt_hilo(*(const float4*)phb0, *(const float4*)(phb0 + 4), sth[2], stl[2]);
  cvt_hilo(*(const float4*)phb1, *(const float4*)(phb1 + 4), sth[3], stl[3]);

  for (int kt = 0; kt < 16; ++kt) {
    __syncthreads();  // barrier A: prev compute done reading LDS
    *(half8*)(ldsXh + c0 * 8) = sth[0];
    *(half8*)(ldsXh + c1 * 8) = sth[1];
    *(half8*)(ldsHh + c0 * 8) = sth[2];
    *(half8*)(ldsHh + c1 * 8) = sth[3];
    *(half8*)(ldsXl + c0 * 8) = stl[0];
    *(half8*)(ldsXl + c1 * 8) = stl[1];
    *(half8*)(ldsHl + c0 * 8) = stl[2];
    *(half8*)(ldsHl + c1 * 8) = stl[3];
    __syncthreads();  // barrier B: lgkm drain only

    // --- prefetch x/h for kt+1 (registers; covered by the MFMA phase) ---
    const int kn = ((kt + 1) & 15) * 32;
    float4 nx0 = *(const float4*)(pxb0 + kn);
    float4 nx1 = *(const float4*)(pxb0 + kn + 4);
    float4 nx2 = *(const float4*)(pxb1 + kn);
    float4 nx3 = *(const float4*)(pxb1 + kn + 4);
    float4 nh0 = *(const float4*)(phb0 + kn);
    float4 nh1 = *(const float4*)(phb0 + kn + 4);
    float4 nh2 = *(const float4*)(phb1 + kn);
    float4 nh3 = *(const float4*)(phb1 + kn + 4);

    // --- compute: 144 MFMA / wave ---
    half8 axh[4], ahh[4];
#pragma unroll
    for (int i = 0; i < 4; ++i) {
      axh[i] = *(const half8*)(ldsXh + ((wm * 4 + i) * 64 + lane) * 8);
      ahh[i] = *(const half8*)(ldsHh + ((wm * 4 + i) * 64 + lane) * 8);
    }
#pragma unroll
    for (int jn = 0; jn < 2; ++jn) {
      const int bo = (wn * 2 + jn) * 512 + lane * 8;
      const size_t tb = ((size_t)(nt * 16 + kt)) * 2048 + bo;
      // B-hi direct from global
      half8 bh_ir = *(const half8*)(whi + tb + 0 * WSTRIDE);
      half8 bh_hr = *(const half8*)(whi + tb + 1 * WSTRIDE);
      half8 bh_iz = *(const half8*)(whi + tb + 2 * WSTRIDE);
      half8 bh_hz = *(const half8*)(whi + tb + 3 * WSTRIDE);
      half8 bh_in = *(const half8*)(whi + tb + 4 * WSTRIDE);
      half8 bh_hn = *(const half8*)(whi + tb + 5 * WSTRIDE);
      // phase 1: B_hi x (A_hi + A_lo)
#pragma unroll
      for (int i = 0; i < 4; ++i) {
        half8 axl = *(const half8*)(ldsXl + ((wm * 4 + i) * 64 + lane) * 8);
        half8 ahl = *(const half8*)(ldsHl + ((wm * 4 + i) * 64 + lane) * 8);
        acc_r[i][jn]  = __builtin_amdgcn_mfma_f32_16x16x32_f16(axh[i], bh_ir, acc_r[i][jn], 0, 0, 0);
        acc_r[i][jn]  = __builtin_amdgcn_mfma_f32_16x16x32_f16(axl,    bh_ir, acc_r[i][jn], 0, 0, 0);
        acc_r[i][jn]  = __builtin_amdgcn_mfma_f32_16x16x32_f16(ahh[i], bh_hr, acc_r[i][jn], 0, 0, 0);
        acc_r[i][jn]  = __builtin_amdgcn_mfma_f32_16x16x32_f16(ahl,    bh_hr, acc_r[i][jn], 0, 0, 0);
        acc_z[i][jn]  = __builtin_amdgcn_mfma_f32_16x16x32_f16(axh[i], bh_iz, acc_z[i][jn], 0, 0, 0);
        acc_z[i][jn]  = __builtin_amdgcn_mfma_f32_16x16x32_f16(axl,    bh_iz, acc_z[i][jn], 0, 0, 0);
        acc_z[i][jn]  = __builtin_amdgcn_mfma_f32_16x16x32_f16(ahh[i], bh_hz, acc_z[i][jn], 0, 0, 0);
        acc_z[i][jn]  = __builtin_amdgcn_mfma_f32_16x16x32_f16(ahl,    bh_hz, acc_z[i][jn], 0, 0, 0);
        acc_in[i][jn] = __builtin_amdgcn_mfma_f32_16x16x32_f16(axh[i], bh_in, acc_in[i][jn], 0, 0, 0);
        acc_in[i][jn] = __builtin_amdgcn_mfma_f32_16x16x32_f16(axl,    bh_in, acc_in[i][jn], 0, 0, 0);
        acc_hn[i][jn] = __builtin_amdgcn_mfma_f32_16x16x32_f16(ahh[i], bh_hn, acc_hn[i][jn], 0, 0, 0);
        acc_hn[i][jn] = __builtin_amdgcn_mfma_f32_16x16x32_f16(ahl,    bh_hn, acc_hn[i][jn], 0, 0, 0);
      }
      // B-lo direct from global; phase 2: A_hi x B_lo
      half8 bl_ir = *(const half8*)(wlo + tb + 0 * WSTRIDE);
      half8 bl_hr = *(const half8*)(wlo + tb + 1 * WSTRIDE);
      half8 bl_iz = *(const half8*)(wlo + tb + 2 * WSTRIDE);
      half8 bl_hz = *(const half8*)(wlo + tb + 3 * WSTRIDE);
      half8 bl_in = *(const half8*)(wlo + tb + 4 * WSTRIDE);
      half8 bl_hn = *(const half8*)(wlo + tb + 5 * WSTRIDE);
#pragma unroll
      for (int i = 0; i < 4; ++i) {
        acc_r[i][jn]  = __builtin_amdgcn_mfma_f32_16x16x32_f16(axh[i], bl_ir, acc_r[i][jn], 0, 0, 0);
        acc_r[i][jn]  = __builtin_amdgcn_mfma_f32_16x16x32_f16(ahh[i], bl_hr, acc_r[i][jn], 0, 0, 0);
        acc_z[i][jn]  = __builtin_amdgcn_mfma_f32_16x16x32_f16(axh[i], bl_iz, acc_z[i][jn], 0, 0, 0);
        acc_z[i][jn]  = __builtin_amdgcn_mfma_f32_16x16x32_f16(ahh[i], bl_hz, acc_z[i][jn], 0, 0, 0);
        acc_in[i][jn] = __builtin_amdgcn_mfma_f32_16x16x32_f16(axh[i], bl_in, acc_in[i][jn], 0, 0, 0);
        acc_hn[i][jn] = __builtin_amdgcn_mfma_f32_16x16x32_f16(ahh[i], bl_hn, acc_hn[i][jn], 0, 0, 0);
      }
    }

    // --- compute tail: convert prefetched data (off the barrier path) ---
    cvt_hilo(nx0, nx1, sth[0], stl[0]);
    cvt_hilo(nx2, nx3, sth[1], stl[1]);
    cvt_hilo(nh0, nh1, sth[2], stl[2]);
    cvt_hilo(nh2, nh3, sth[3], stl[3]);
  }

  // --- epilogue: gates + h_new. C/D layout: col = lane&15, row = quad*4+reg ---
  const int quad = lane >> 4;
  const int col = lane & 15;
#pragma unroll
  for (int i = 0; i < 4; ++i) {
    const int mbase = m0 + wm * 64 + i * 16 + quad * 4;
#pragma unroll
    for (int jn = 0; jn < 2; ++jn) {
      const int n = n0 + wn * 32 + jn * 16 + col;
      const float vbr = br[n], vbz = bz[n], vbn = bn[n];
#pragma unroll
      for (int r = 0; r < 4; ++r) {
        const int m = mbase + r;
        const float gr = acc_r[i][jn][r] + vbr;
        const float gz = acc_z[i][jn][r] + vbz;
        const float rg = 1.0f / (1.0f + __expf(-gr));
        const float zg = 1.0f / (1.0f + __expf(-gz));
        const float gn = acc_in[i][jn][r] + rg * acc_hn[i][jn][r] + vbn;
        const float e2 = __expf(2.0f * gn);
        const float ntv = 1.0f - 2.0f / (e2 + 1.0f);
        const float hp = h[(size_t)m * 512 + n];
        out[(size_t)m * 512 + n] = (1.0f - zg) * ntv + zg * hp;
      }
    }
  }
}

extern "C" void kernel_launch(void* const* d_in, const int* in_sizes, int n_in,
                              void* d_out, int out_size, void* d_ws, size_t ws_size,
                              hipStream_t stream) {
  const float* x   = (const float*)d_in[0];
  const float* h   = (const float*)d_in[1];
  const float* Wir = (const float*)d_in[2];
  const float* Whr = (const float*)d_in[3];
  const float* br  = (const float*)d_in[4];
  const float* Wiz = (const float*)d_in[5];
  const float* Whz = (const float*)d_in[6];
  const float* bz  = (const float*)d_in[7];
  const float* Win = (const float*)d_in[8];
  const float* Whn = (const float*)d_in[9];
  const float* bn  = (const float*)d_in[10];
  float* out = (float*)d_out;
  _Float16* wperm = (_Float16*)d_ws;  // needs 2 * 6*512*512*2 = 6.3 MB

  permute_w<<<768, 256, 0, stream>>>(Wir, Whr, Wiz, Whz, Win, Whn, wperm);
  gru_fused<<<1024, 256, 0, stream>>>(x, h, wperm, br, bz, bn, out);
}